// Round 20
// baseline (86.250 us; speedup 1.0000x reference)
//
#include <hip/hip_runtime.h>
#include <hip/hip_bf16.h>
#include <stdint.h>

// B=8, C=256, H=W=64 (N=4096), T=512
// out0 = F_s + (softmax(Fs_t @ Ft^T / sqrt(T)) @ Ft) in [B][C][N] layout, fp32
// out1 = P^T @ Fs_t   [B][T][C] fp32

typedef __attribute__((ext_vector_type(8))) short short8v;   // 8 bf16
typedef __attribute__((ext_vector_type(4))) float float4v;

#define MFMA16(a, b, c) __builtin_amdgcn_mfma_f32_16x16x32_bf16(a, b, c, 0, 0, 0)
#define SCALE 0.04419417382415922f  // 1/sqrt(512)

static __device__ __forceinline__ unsigned short f2bf(float f) {
  union { float f; uint32_t u; } v; v.f = f;
  uint32_t r = v.u + 0x7fffu + ((v.u >> 16) & 1u);   // RNE
  return (unsigned short)(r >> 16);
}
static __device__ __forceinline__ float bf2f(unsigned short u) {
  union { uint32_t u; float f; } v; v.u = (uint32_t)u << 16;
  return v.f;
}

// async global->LDS, 16B per lane; LDS dest is wave-uniform base + lane*16
static __device__ __forceinline__ void gload16(const void* g, void* l) {
  __builtin_amdgcn_global_load_lds(
      (const __attribute__((address_space(1))) void*)g,
      (__attribute__((address_space(3))) void*)l, 16, 0, 0);
}

// ---------- cast + transpose (unchanged) ----------
__global__ __launch_bounds__(256) void k_cast_transpose(
    const float* __restrict__ src, unsigned short* __restrict__ dstC,
    unsigned short* __restrict__ dstT, int R, int Cd) {
  __shared__ unsigned short tile[32][33];
  const size_t zoff = (size_t)blockIdx.z * R * Cd;
  const float* s = src + zoff;
  unsigned short* dc = dstC + zoff;
  unsigned short* dt = dstT + zoff;
  const int c0 = blockIdx.x * 32, r0 = blockIdx.y * 32;
  const int tid = threadIdx.x;
  const int r = tid >> 3, c4 = (tid & 7) * 4;

  float4 v = *(const float4*)&s[(size_t)(r0 + r) * Cd + c0 + c4];
  ushort4 bq;
  bq.x = f2bf(v.x); bq.y = f2bf(v.y); bq.z = f2bf(v.z); bq.w = f2bf(v.w);
  *(ushort4*)&dc[(size_t)(r0 + r) * Cd + c0 + c4] = bq;
  tile[r][c4 + 0] = bq.x; tile[r][c4 + 1] = bq.y;
  tile[r][c4 + 2] = bq.z; tile[r][c4 + 3] = bq.w;
  __syncthreads();
  ushort4 o;
  o.x = tile[c4 + 0][r]; o.y = tile[c4 + 1][r];
  o.z = tile[c4 + 2][r]; o.w = tile[c4 + 3][r];
  *(ushort4*)&dt[(size_t)(c0 + r) * R + r0 + c4] = o;
}

// ---------- k_attn (r19, unchanged): 2q x 2t wave split, counted-vmcnt ----------
__global__ __launch_bounds__(256, 2) void k_attn(
    const unsigned short* __restrict__ Qg, const unsigned short* __restrict__ Kg,
    const unsigned short* __restrict__ VTg, const unsigned short* __restrict__ QTg,
    float* __restrict__ out0, unsigned short* __restrict__ PTg) {
  __shared__ char smem[81920];

  const int tid = threadIdx.x;
  const int wave = tid >> 6, lane = tid & 63;
  const int l16 = lane & 15, lhi = lane >> 4;
  const int wq = wave >> 1, wt = wave & 1;
  const int b = blockIdx.x & 7, nb = blockIdx.x >> 3;
  const int n0 = nb * 64;
  const int cx = (l16 & 7) << 4;             // read swizzle

  const unsigned short* Qb = Qg + (size_t)b * 4096 * 256;
  const char* Kb = (const char*)(Kg + (size_t)b * 512 * 256);
  const char* VTb = (const char*)(VTg + (size_t)b * 256 * 512);

#define STAGE_K16(c_) do {                                                  \
    const char* src_ = Kb + (c_) * 16384;                                   \
    char* dst_ = smem + ((c_) & 3) * 16384;                                 \
    _Pragma("unroll")                                                       \
    for (int i = 0; i < 4; i++) {                                           \
      const int off = (tid + i * 256) * 16;                                 \
      gload16(src_ + (off ^ (((off >> 9) & 7) << 4)), dst_ + off);          \
    } } while (0)

#define STAGE_VT16(v_) do {                                                 \
    const int ch_ = (v_) & 1, tau_ = (v_) >> 1;                             \
    char* dst_ = smem + ((v_) & 3) * 16384;                                 \
    _Pragma("unroll")                                                       \
    for (int i = 0; i < 4; i++) {                                           \
      const int off = (tid + i * 256) * 16;                                 \
      const int r_ = off >> 7, ic_ = off & 127;                             \
      gload16(VTb + (size_t)(ch_ * 128 + r_) * 1024 + tau_ * 128            \
                  + (ic_ ^ ((r_ & 7) << 4)),                                \
              dst_ + off);                                                  \
    } } while (0)

#define PS_WRITE(tau_) do {                                                 \
    char* PsN = smem + 65536 + ((tau_) & 1) * 8192 + wq * 4096;             \
    _Pragma("unroll")                                                       \
    for (int qt = 0; qt < 2; qt++)                                          \
      _Pragma("unroll")                                                     \
      for (int cc = 0; cc < 2; cc++)                                        \
        _Pragma("unroll")                                                   \
        for (int r = 0; r < 4; r++) {                                       \
          const int q = qt * 16 + lhi * 4 + r;                              \
          const int t2 = cc * 32 + wt * 16 + l16;                           \
          const uint32_t w = pk[(qt * 16 + (tau_) * 2 + cc) * 2 + (r >> 1)];\
          *(unsigned short*)(PsN + ((q * 128 + t2 * 2) ^ ((q & 7) << 4))) = \
              (unsigned short)(w >> ((r & 1) * 16));                        \
        } } while (0)

  // ---- Q A-frags: 2 q-tiles (rows = q = wq*32 + qt*16 + l16) ----
  short8v aQ[2][8];
#pragma unroll
  for (int qt = 0; qt < 2; qt++)
#pragma unroll
    for (int kc = 0; kc < 8; kc++)
      aQ[qt][kc] = *(const short8v*)(Qb +
          (size_t)(n0 + wq * 32 + qt * 16 + l16) * 256 + kc * 32 + lhi * 8);

  float4v acc[2][16];
#pragma unroll
  for (int qt = 0; qt < 2; qt++)
#pragma unroll
    for (int c = 0; c < 16; c++) acc[qt][c] = (float4v)0.f;

  // ---- phase 1: S = Q @ K^T, 16 chunks, 3-deep pipeline ----
  STAGE_K16(0); STAGE_K16(1); STAGE_K16(2);
#pragma unroll
  for (int c = 0; c < 16; c++) {
    asm volatile("s_waitcnt vmcnt(8)" ::: "memory");
    __builtin_amdgcn_s_barrier();
    if (c < 13) STAGE_K16(c + 3);
    else        STAGE_VT16(c - 13);
    const char* rb = smem + (c & 3) * 16384 + (wt * 16 + l16) * 512;
#pragma unroll
    for (int kc = 0; kc < 8; kc++) {
      short8v bf = *(const short8v*)(rb + ((kc * 64 + lhi * 16) ^ cx));
      acc[0][c] = MFMA16(aQ[0][kc], bf, acc[0][c]);
      acc[1][c] = MFMA16(aQ[1][kc], bf, acc[1][c]);
    }
    asm volatile("s_waitcnt lgkmcnt(0)" ::: "memory");
  }

  // ---- softmax: in-wave reduce + cross-wave wt-pair combine via red ----
  float* red = (float*)(smem + 65536 + 8192);  // 512 f32, parity-1 area
  float mx[2][4];
#pragma unroll
  for (int qt = 0; qt < 2; qt++)
#pragma unroll
    for (int r = 0; r < 4; r++) {
      float m = acc[qt][0][r];
#pragma unroll
      for (int c = 1; c < 16; c++) m = fmaxf(m, acc[qt][c][r]);
      m = fmaxf(m, __shfl_xor(m, 1));
      m = fmaxf(m, __shfl_xor(m, 2));
      m = fmaxf(m, __shfl_xor(m, 4));
      m = fmaxf(m, __shfl_xor(m, 8));
      mx[qt][r] = m;
    }
  if (l16 == 0) {
#pragma unroll
    for (int qt = 0; qt < 2; qt++)
#pragma unroll
      for (int r = 0; r < 4; r++)
        red[(wq * 2 + wt) * 32 + qt * 16 + lhi * 4 + r] = mx[qt][r];
  }
  __builtin_amdgcn_s_barrier();
  asm volatile("s_waitcnt lgkmcnt(0)" ::: "memory");
#pragma unroll
  for (int qt = 0; qt < 2; qt++)
#pragma unroll
    for (int r = 0; r < 4; r++) {
      const int q = qt * 16 + lhi * 4 + r;
      mx[qt][r] = fmaxf(red[(wq * 2 + 0) * 32 + q], red[(wq * 2 + 1) * 32 + q]);
    }
  float sm[2][4];
#pragma unroll
  for (int qt = 0; qt < 2; qt++)
#pragma unroll
    for (int r = 0; r < 4; r++) {
      float s = 0.f;
#pragma unroll
      for (int c = 0; c < 16; c++) {
        float p = __expf((acc[qt][c][r] - mx[qt][r]) * SCALE);
        acc[qt][c][r] = p;
        s += p;
      }
      s += __shfl_xor(s, 1); s += __shfl_xor(s, 2);
      s += __shfl_xor(s, 4); s += __shfl_xor(s, 8);
      sm[qt][r] = s;
    }
  if (l16 == 0) {
#pragma unroll
    for (int qt = 0; qt < 2; qt++)
#pragma unroll
      for (int r = 0; r < 4; r++)
        red[128 + (wq * 2 + wt) * 32 + qt * 16 + lhi * 4 + r] = sm[qt][r];
  }
  __builtin_amdgcn_s_barrier();
  asm volatile("s_waitcnt lgkmcnt(0)" ::: "memory");
#pragma unroll
  for (int qt = 0; qt < 2; qt++)
#pragma unroll
    for (int r = 0; r < 4; r++) {
      const int q = qt * 16 + lhi * 4 + r;
      sm[qt][r] = 1.0f / (red[128 + (wq * 2 + 0) * 32 + q] +
                          red[128 + (wq * 2 + 1) * 32 + q]);
    }

  // ---- pack P into bf16 regs: pk[(qt*16+c)*2+h] ----
  uint32_t pk[64];
#pragma unroll
  for (int qt = 0; qt < 2; qt++)
#pragma unroll
    for (int c = 0; c < 16; c++)
#pragma unroll
      for (int h = 0; h < 2; h++)
        pk[(qt * 16 + c) * 2 + h] =
            (uint32_t)f2bf(acc[qt][c][2 * h] * sm[qt][2 * h]) |
            ((uint32_t)f2bf(acc[qt][c][2 * h + 1] * sm[qt][2 * h + 1]) << 16);

  PS_WRITE(0);

  // ---- phase 2: PV, 16 chunks (v = tau*2+ch), same pipeline ----
  float4v oacc[8][2];
#pragma unroll
  for (int ct = 0; ct < 8; ct++)
#pragma unroll
    for (int qt = 0; qt < 2; qt++) oacc[ct][qt] = (float4v)0.f;

  unsigned short* PTb = PTg + (size_t)b * 512 * 4096;

#pragma unroll
  for (int v = 0; v < 16; v++) {
    if (v <= 13)      asm volatile("s_waitcnt vmcnt(8)" ::: "memory");
    else if (v == 14) asm volatile("s_waitcnt vmcnt(4)" ::: "memory");
    else              asm volatile("s_waitcnt vmcnt(0)" ::: "memory");
    __builtin_amdgcn_s_barrier();
    if (v < 13) STAGE_VT16(v + 3);
    const int tau = v >> 1, ch = v & 1;
    char* PsT = smem + 65536 + (tau & 1) * 8192 + wq * 4096;
    if (ch == wt) {
      short8v pb00 = *(const short8v*)(PsT + (((0 * 16 + l16) * 128 + 0 * 64 + lhi * 16) ^ cx));
      short8v pb01 = *(const short8v*)(PsT + (((0 * 16 + l16) * 128 + 1 * 64 + lhi * 16) ^ cx));
      short8v pb10 = *(const short8v*)(PsT + (((1 * 16 + l16) * 128 + 0 * 64 + lhi * 16) ^ cx));
      short8v pb11 = *(const short8v*)(PsT + (((1 * 16 + l16) * 128 + 1 * 64 + lhi * 16) ^ cx));
      const char* bufp = smem + (v & 3) * 16384;
#pragma unroll
      for (int ct = 0; ct < 8; ct++) {
        const char* rb = bufp + (ct * 16 + l16) * 128;   // row&7 == l16&7
        short8v a0 = *(const short8v*)(rb + ((lhi * 16) ^ cx));
        oacc[ct][0] = MFMA16(a0, pb00, oacc[ct][0]);
        oacc[ct][1] = MFMA16(a0, pb10, oacc[ct][1]);
        short8v a1 = *(const short8v*)(rb + ((64 + lhi * 16) ^ cx));
        oacc[ct][0] = MFMA16(a1, pb01, oacc[ct][0]);
        oacc[ct][1] = MFMA16(a1, pb11, oacc[ct][1]);
      }
    }
    if (ch == 1) {
      if (tau < 7) {
        const int taun = tau + 1;
        PS_WRITE(taun);
      }
      {
        const int t2 = wt * 32 + (lane & 31);
        const int cg = (lane >> 5) * 16;
        unsigned short tmp[16];
#pragma unroll
        for (int j = 0; j < 16; j++) {
          const int q = cg + j;
          tmp[j] = *(const unsigned short*)(PsT + ((q * 128 + t2 * 2) ^ ((q & 7) << 4)));
        }
        unsigned short* dst = PTb + (size_t)(tau * 64 + t2) * 4096 + n0 + wq * 32 + cg;
        *(int4*)dst = *(int4*)&tmp[0];
        *(int4*)(dst + 8) = *(int4*)&tmp[8];
      }
    }
    asm volatile("s_waitcnt lgkmcnt(0)" ::: "memory");
  }

  // ---- epilogue: out0[b][c][n] = oacc + residual(QT bf16) ----
  const unsigned short* QTb = QTg + (size_t)b * 256 * 4096;
  float* o0 = out0 + (size_t)b * 256 * 4096;
#pragma unroll
  for (int ct = 0; ct < 8; ct++)
#pragma unroll
    for (int qt = 0; qt < 2; qt++)
#pragma unroll
      for (int r = 0; r < 4; r++) {
        const int cgl = wt * 128 + ct * 16 + lhi * 4 + r;
        const int n = n0 + wq * 32 + qt * 16 + l16;
        const size_t off = (size_t)cgl * 4096 + n;
        o0[off] = oacc[ct][qt][r] + bf2f(QTb[off]);
      }
#undef STAGE_K16
#undef STAGE_VT16
#undef PS_WRITE
}

// ---------- k_ptq v6: split-K 4, bf16 partials (r20) ----------
// grid 256 (8 t-blocks x 8 b x 4 ksl; bid===b mod 8 -> XCD-grouped QT slice).
// Each block: 64 t x 256 c over a 1024-n slice (16 chunks). Partials stored
// bf16 (8 MB vs 32 MB fp32): partial magnitudes ~0.25, bf16 adds ~1e-3 abs.
__global__ __launch_bounds__(256, 2) void k_ptq(
    const unsigned short* __restrict__ PTg, const unsigned short* __restrict__ QTg,
    unsigned short* __restrict__ part) {
  __shared__ char smem[65536];

  const int tid = threadIdx.x;
  const int wave = tid >> 6, lane = tid & 63;
  const int l16 = lane & 15, lhi = lane >> 4;
  const int bid = blockIdx.x;
  const int t0 = (bid >> 5) * 64;
  const int grp = bid & 31;
  const int b = grp & 7, ksl = grp >> 3;     // ksl 0..3
  const int cx = (l16 & 7) << 4;

  const unsigned short* PTrow =
      PTg + ((size_t)(b * 512 + t0 + wave * 16 + l16)) * 4096 + ksl * 1024 + lhi * 8;
  const char* QTb = (const char*)(QTg + (size_t)b * 256 * 4096 + ksl * 1024);

#define STAGE_Q(c_, buf_) do {                                              \
    _Pragma("unroll")                                                       \
    for (int i = 0; i < 8; i++) {                                           \
      const int off = (tid + i * 256) * 16;                                 \
      const int r_ = off >> 7, ic_ = off & 127;                             \
      gload16(QTb + (size_t)r_ * 8192 + (c_) * 128 + (ic_ ^ ((r_ & 7) << 4)), \
              smem + (buf_) * 32768 + off);                                 \
    } } while (0)

  float4v acc[16];
#pragma unroll
  for (int ct = 0; ct < 16; ct++) acc[ct] = (float4v)0.f;

  STAGE_Q(0, 0);
  __syncthreads();
#pragma unroll
  for (int c = 0; c < 16; c++) {
    const int buf = c & 1;
    short8v pa0 = *(const short8v*)(PTrow + c * 64);
    short8v pa1 = *(const short8v*)(PTrow + c * 64 + 32);
    if (c < 15) STAGE_Q(c + 1, buf ^ 1);
#pragma unroll
    for (int ct = 0; ct < 16; ct++) {
      const int row = ct * 16 + l16;             // row&7 == l16&7
      const char* rb = smem + buf * 32768 + row * 128;
      short8v b0 = *(const short8v*)(rb + ((lhi * 16) ^ cx));
      acc[ct] = MFMA16(pa0, b0, acc[ct]);
      short8v b1 = *(const short8v*)(rb + ((64 + lhi * 16) ^ cx));
      acc[ct] = MFMA16(pa1, b1, acc[ct]);
    }
    __syncthreads();
  }

  // partial[ksl][b][t][c] bf16 stores (l16 -> 16 contiguous c)
  unsigned short* pout = part + (((size_t)ksl * 8 + b) * 512 + t0 + wave * 16) * 256;
#pragma unroll
  for (int ct = 0; ct < 16; ct++)
#pragma unroll
    for (int r = 0; r < 4; r++)
      pout[(lhi * 4 + r) * 256 + ct * 16 + l16] = f2bf(acc[ct][r]);
#undef STAGE_Q
}

// ---------- k_red v2: out1 = sum over 4 bf16 partials ----------
// grid 512 x 256 thr; each thread sums 8 elements (short8v loads).
__global__ __launch_bounds__(256) void k_red(
    const unsigned short* __restrict__ part, float* __restrict__ out1) {
  const size_t g = (size_t)(blockIdx.x * 256 + threadIdx.x) * 8;
  float s[8];
#pragma unroll
  for (int j = 0; j < 8; j++) s[j] = 0.f;
#pragma unroll
  for (int ksl = 0; ksl < 4; ksl++) {
    short8v v = *(const short8v*)(part + (size_t)ksl * 1048576 + g);
#pragma unroll
    for (int j = 0; j < 8; j++) s[j] += bf2f((unsigned short)v[j]);
  }
  float4 o0 = {s[0], s[1], s[2], s[3]};
  float4 o1 = {s[4], s[5], s[6], s[7]};
  *(float4*)(out1 + g) = o0;
  *(float4*)(out1 + g + 4) = o1;
}

extern "C" void kernel_launch(void* const* d_in, const int* in_sizes, int n_in,
                              void* d_out, int out_size, void* d_ws, size_t ws_size,
                              hipStream_t stream) {
  const float* Fs = (const float*)d_in[0];   // [8][256][4096]
  const float* Ft = (const float*)d_in[1];   // [8][512][256]
  float* out0 = (float*)d_out;               // [8][256][4096]
  float* out1 = out0 + (size_t)8 * 256 * 4096;  // [8][512][256]

  unsigned short* ws = (unsigned short*)d_ws;
  unsigned short* Q  = ws;                // [8][4096][256]  16 MB
  unsigned short* QT = Q + 8388608;       // [8][256][4096]  16 MB
  unsigned short* K  = QT + 8388608;      // [8][512][256]    2 MB
  unsigned short* VT = K + 1048576;       // [8][256][512]    2 MB
  unsigned short* PT = VT + 1048576;      // [8][512][4096]  32 MB
  unsigned short* part = PT + 16777216;   // [4][8][512][256] bf16, 8 MB
  // total ws use: 76,546,048 bytes

  k_cast_transpose<<<dim3(128, 8, 8), 256, 0, stream>>>(Fs, QT, Q, 256, 4096);
  k_cast_transpose<<<dim3(8, 16, 8), 256, 0, stream>>>(Ft, K, VT, 512, 256);
  k_attn<<<dim3(512), 256, 0, stream>>>(Q, K, VT, QT, out0, PT);
  k_ptq<<<dim3(256), 256, 0, stream>>>(PT, QT, part);
  k_red<<<dim3(512), 256, 0, stream>>>(part, out1);
}

// Round 21
// 76.101 us; speedup vs baseline: 1.1334x; 1.1334x over previous
//
#include <hip/hip_runtime.h>
#include <hip/hip_bf16.h>
#include <stdint.h>

// B=8, C=256, H=W=64 (N=4096), T=512
// out0 = F_s + (softmax(Fs_t @ Ft^T / sqrt(T)) @ Ft) in [B][C][N] layout, fp32
// out1 = P^T @ Fs_t   [B][T][C] fp32

typedef __attribute__((ext_vector_type(8))) short short8v;   // 8 bf16
typedef __attribute__((ext_vector_type(4))) float float4v;

#define MFMA16(a, b, c) __builtin_amdgcn_mfma_f32_16x16x32_bf16(a, b, c, 0, 0, 0)
#define SCALE 0.04419417382415922f  // 1/sqrt(512)

static __device__ __forceinline__ unsigned short f2bf(float f) {
  union { float f; uint32_t u; } v; v.f = f;
  uint32_t r = v.u + 0x7fffu + ((v.u >> 16) & 1u);   // RNE
  return (unsigned short)(r >> 16);
}
static __device__ __forceinline__ float bf2f(unsigned short u) {
  union { uint32_t u; float f; } v; v.u = (uint32_t)u << 16;
  return v.f;
}

// async global->LDS, 16B per lane; LDS dest is wave-uniform base + lane*16
static __device__ __forceinline__ void gload16(const void* g, void* l) {
  __builtin_amdgcn_global_load_lds(
      (const __attribute__((address_space(1))) void*)g,
      (__attribute__((address_space(3))) void*)l, 16, 0, 0);
}

// ---------- cast + transpose (unchanged) ----------
__global__ __launch_bounds__(256) void k_cast_transpose(
    const float* __restrict__ src, unsigned short* __restrict__ dstC,
    unsigned short* __restrict__ dstT, int R, int Cd) {
  __shared__ unsigned short tile[32][33];
  const size_t zoff = (size_t)blockIdx.z * R * Cd;
  const float* s = src + zoff;
  unsigned short* dc = dstC + zoff;
  unsigned short* dt = dstT + zoff;
  const int c0 = blockIdx.x * 32, r0 = blockIdx.y * 32;
  const int tid = threadIdx.x;
  const int r = tid >> 3, c4 = (tid & 7) * 4;

  float4 v = *(const float4*)&s[(size_t)(r0 + r) * Cd + c0 + c4];
  ushort4 bq;
  bq.x = f2bf(v.x); bq.y = f2bf(v.y); bq.z = f2bf(v.z); bq.w = f2bf(v.w);
  *(ushort4*)&dc[(size_t)(r0 + r) * Cd + c0 + c4] = bq;
  tile[r][c4 + 0] = bq.x; tile[r][c4 + 1] = bq.y;
  tile[r][c4 + 2] = bq.z; tile[r][c4 + 3] = bq.w;
  __syncthreads();
  ushort4 o;
  o.x = tile[c4 + 0][r]; o.y = tile[c4 + 1][r];
  o.z = tile[c4 + 2][r]; o.w = tile[c4 + 3][r];
  *(ushort4*)&dt[(size_t)(c0 + r) * R + r0 + c4] = o;
}

// ---------- k_attn (r19, unchanged): 2q x 2t wave split, counted-vmcnt ----------
__global__ __launch_bounds__(256, 2) void k_attn(
    const unsigned short* __restrict__ Qg, const unsigned short* __restrict__ Kg,
    const unsigned short* __restrict__ VTg, const unsigned short* __restrict__ QTg,
    float* __restrict__ out0, unsigned short* __restrict__ PTg) {
  __shared__ char smem[81920];

  const int tid = threadIdx.x;
  const int wave = tid >> 6, lane = tid & 63;
  const int l16 = lane & 15, lhi = lane >> 4;
  const int wq = wave >> 1, wt = wave & 1;
  const int b = blockIdx.x & 7, nb = blockIdx.x >> 3;
  const int n0 = nb * 64;
  const int cx = (l16 & 7) << 4;             // read swizzle

  const unsigned short* Qb = Qg + (size_t)b * 4096 * 256;
  const char* Kb = (const char*)(Kg + (size_t)b * 512 * 256);
  const char* VTb = (const char*)(VTg + (size_t)b * 256 * 512);

#define STAGE_K16(c_) do {                                                  \
    const char* src_ = Kb + (c_) * 16384;                                   \
    char* dst_ = smem + ((c_) & 3) * 16384;                                 \
    _Pragma("unroll")                                                       \
    for (int i = 0; i < 4; i++) {                                           \
      const int off = (tid + i * 256) * 16;                                 \
      gload16(src_ + (off ^ (((off >> 9) & 7) << 4)), dst_ + off);          \
    } } while (0)

#define STAGE_VT16(v_) do {                                                 \
    const int ch_ = (v_) & 1, tau_ = (v_) >> 1;                             \
    char* dst_ = smem + ((v_) & 3) * 16384;                                 \
    _Pragma("unroll")                                                       \
    for (int i = 0; i < 4; i++) {                                           \
      const int off = (tid + i * 256) * 16;                                 \
      const int r_ = off >> 7, ic_ = off & 127;                             \
      gload16(VTb + (size_t)(ch_ * 128 + r_) * 1024 + tau_ * 128            \
                  + (ic_ ^ ((r_ & 7) << 4)),                                \
              dst_ + off);                                                  \
    } } while (0)

#define PS_WRITE(tau_) do {                                                 \
    char* PsN = smem + 65536 + ((tau_) & 1) * 8192 + wq * 4096;             \
    _Pragma("unroll")                                                       \
    for (int qt = 0; qt < 2; qt++)                                          \
      _Pragma("unroll")                                                     \
      for (int cc = 0; cc < 2; cc++)                                        \
        _Pragma("unroll")                                                   \
        for (int r = 0; r < 4; r++) {                                       \
          const int q = qt * 16 + lhi * 4 + r;                              \
          const int t2 = cc * 32 + wt * 16 + l16;                           \
          const uint32_t w = pk[(qt * 16 + (tau_) * 2 + cc) * 2 + (r >> 1)];\
          *(unsigned short*)(PsN + ((q * 128 + t2 * 2) ^ ((q & 7) << 4))) = \
              (unsigned short)(w >> ((r & 1) * 16));                        \
        } } while (0)

  // ---- Q A-frags: 2 q-tiles (rows = q = wq*32 + qt*16 + l16) ----
  short8v aQ[2][8];
#pragma unroll
  for (int qt = 0; qt < 2; qt++)
#pragma unroll
    for (int kc = 0; kc < 8; kc++)
      aQ[qt][kc] = *(const short8v*)(Qb +
          (size_t)(n0 + wq * 32 + qt * 16 + l16) * 256 + kc * 32 + lhi * 8);

  float4v acc[2][16];
#pragma unroll
  for (int qt = 0; qt < 2; qt++)
#pragma unroll
    for (int c = 0; c < 16; c++) acc[qt][c] = (float4v)0.f;

  // ---- phase 1: S = Q @ K^T, 16 chunks, 3-deep pipeline ----
  STAGE_K16(0); STAGE_K16(1); STAGE_K16(2);
#pragma unroll
  for (int c = 0; c < 16; c++) {
    asm volatile("s_waitcnt vmcnt(8)" ::: "memory");
    __builtin_amdgcn_s_barrier();
    if (c < 13) STAGE_K16(c + 3);
    else        STAGE_VT16(c - 13);
    const char* rb = smem + (c & 3) * 16384 + (wt * 16 + l16) * 512;
#pragma unroll
    for (int kc = 0; kc < 8; kc++) {
      short8v bf = *(const short8v*)(rb + ((kc * 64 + lhi * 16) ^ cx));
      acc[0][c] = MFMA16(aQ[0][kc], bf, acc[0][c]);
      acc[1][c] = MFMA16(aQ[1][kc], bf, acc[1][c]);
    }
    asm volatile("s_waitcnt lgkmcnt(0)" ::: "memory");
  }

  // ---- softmax: in-wave reduce + cross-wave wt-pair combine via red ----
  float* red = (float*)(smem + 65536 + 8192);  // 512 f32, parity-1 area
  float mx[2][4];
#pragma unroll
  for (int qt = 0; qt < 2; qt++)
#pragma unroll
    for (int r = 0; r < 4; r++) {
      float m = acc[qt][0][r];
#pragma unroll
      for (int c = 1; c < 16; c++) m = fmaxf(m, acc[qt][c][r]);
      m = fmaxf(m, __shfl_xor(m, 1));
      m = fmaxf(m, __shfl_xor(m, 2));
      m = fmaxf(m, __shfl_xor(m, 4));
      m = fmaxf(m, __shfl_xor(m, 8));
      mx[qt][r] = m;
    }
  if (l16 == 0) {
#pragma unroll
    for (int qt = 0; qt < 2; qt++)
#pragma unroll
      for (int r = 0; r < 4; r++)
        red[(wq * 2 + wt) * 32 + qt * 16 + lhi * 4 + r] = mx[qt][r];
  }
  __builtin_amdgcn_s_barrier();
  asm volatile("s_waitcnt lgkmcnt(0)" ::: "memory");
#pragma unroll
  for (int qt = 0; qt < 2; qt++)
#pragma unroll
    for (int r = 0; r < 4; r++) {
      const int q = qt * 16 + lhi * 4 + r;
      mx[qt][r] = fmaxf(red[(wq * 2 + 0) * 32 + q], red[(wq * 2 + 1) * 32 + q]);
    }
  float sm[2][4];
#pragma unroll
  for (int qt = 0; qt < 2; qt++)
#pragma unroll
    for (int r = 0; r < 4; r++) {
      float s = 0.f;
#pragma unroll
      for (int c = 0; c < 16; c++) {
        float p = __expf((acc[qt][c][r] - mx[qt][r]) * SCALE);
        acc[qt][c][r] = p;
        s += p;
      }
      s += __shfl_xor(s, 1); s += __shfl_xor(s, 2);
      s += __shfl_xor(s, 4); s += __shfl_xor(s, 8);
      sm[qt][r] = s;
    }
  if (l16 == 0) {
#pragma unroll
    for (int qt = 0; qt < 2; qt++)
#pragma unroll
      for (int r = 0; r < 4; r++)
        red[128 + (wq * 2 + wt) * 32 + qt * 16 + lhi * 4 + r] = sm[qt][r];
  }
  __builtin_amdgcn_s_barrier();
  asm volatile("s_waitcnt lgkmcnt(0)" ::: "memory");
#pragma unroll
  for (int qt = 0; qt < 2; qt++)
#pragma unroll
    for (int r = 0; r < 4; r++) {
      const int q = qt * 16 + lhi * 4 + r;
      sm[qt][r] = 1.0f / (red[128 + (wq * 2 + 0) * 32 + q] +
                          red[128 + (wq * 2 + 1) * 32 + q]);
    }

  // ---- pack P into bf16 regs: pk[(qt*16+c)*2+h] ----
  uint32_t pk[64];
#pragma unroll
  for (int qt = 0; qt < 2; qt++)
#pragma unroll
    for (int c = 0; c < 16; c++)
#pragma unroll
      for (int h = 0; h < 2; h++)
        pk[(qt * 16 + c) * 2 + h] =
            (uint32_t)f2bf(acc[qt][c][2 * h] * sm[qt][2 * h]) |
            ((uint32_t)f2bf(acc[qt][c][2 * h + 1] * sm[qt][2 * h + 1]) << 16);

  PS_WRITE(0);

  // ---- phase 2: PV, 16 chunks (v = tau*2+ch), same pipeline ----
  float4v oacc[8][2];
#pragma unroll
  for (int ct = 0; ct < 8; ct++)
#pragma unroll
    for (int qt = 0; qt < 2; qt++) oacc[ct][qt] = (float4v)0.f;

  unsigned short* PTb = PTg + (size_t)b * 512 * 4096;

#pragma unroll
  for (int v = 0; v < 16; v++) {
    if (v <= 13)      asm volatile("s_waitcnt vmcnt(8)" ::: "memory");
    else if (v == 14) asm volatile("s_waitcnt vmcnt(4)" ::: "memory");
    else              asm volatile("s_waitcnt vmcnt(0)" ::: "memory");
    __builtin_amdgcn_s_barrier();
    if (v < 13) STAGE_VT16(v + 3);
    const int tau = v >> 1, ch = v & 1;
    char* PsT = smem + 65536 + (tau & 1) * 8192 + wq * 4096;
    if (ch == wt) {
      short8v pb00 = *(const short8v*)(PsT + (((0 * 16 + l16) * 128 + 0 * 64 + lhi * 16) ^ cx));
      short8v pb01 = *(const short8v*)(PsT + (((0 * 16 + l16) * 128 + 1 * 64 + lhi * 16) ^ cx));
      short8v pb10 = *(const short8v*)(PsT + (((1 * 16 + l16) * 128 + 0 * 64 + lhi * 16) ^ cx));
      short8v pb11 = *(const short8v*)(PsT + (((1 * 16 + l16) * 128 + 1 * 64 + lhi * 16) ^ cx));
      const char* bufp = smem + (v & 3) * 16384;
#pragma unroll
      for (int ct = 0; ct < 8; ct++) {
        const char* rb = bufp + (ct * 16 + l16) * 128;   // row&7 == l16&7
        short8v a0 = *(const short8v*)(rb + ((lhi * 16) ^ cx));
        oacc[ct][0] = MFMA16(a0, pb00, oacc[ct][0]);
        oacc[ct][1] = MFMA16(a0, pb10, oacc[ct][1]);
        short8v a1 = *(const short8v*)(rb + ((64 + lhi * 16) ^ cx));
        oacc[ct][0] = MFMA16(a1, pb01, oacc[ct][0]);
        oacc[ct][1] = MFMA16(a1, pb11, oacc[ct][1]);
      }
    }
    if (ch == 1) {
      if (tau < 7) {
        const int taun = tau + 1;
        PS_WRITE(taun);
      }
      {
        const int t2 = wt * 32 + (lane & 31);
        const int cg = (lane >> 5) * 16;
        unsigned short tmp[16];
#pragma unroll
        for (int j = 0; j < 16; j++) {
          const int q = cg + j;
          tmp[j] = *(const unsigned short*)(PsT + ((q * 128 + t2 * 2) ^ ((q & 7) << 4)));
        }
        unsigned short* dst = PTb + (size_t)(tau * 64 + t2) * 4096 + n0 + wq * 32 + cg;
        *(int4*)dst = *(int4*)&tmp[0];
        *(int4*)(dst + 8) = *(int4*)&tmp[8];
      }
    }
    asm volatile("s_waitcnt lgkmcnt(0)" ::: "memory");
  }

  // ---- epilogue: out0[b][c][n] = oacc + residual(QT bf16) ----
  const unsigned short* QTb = QTg + (size_t)b * 256 * 4096;
  float* o0 = out0 + (size_t)b * 256 * 4096;
#pragma unroll
  for (int ct = 0; ct < 8; ct++)
#pragma unroll
    for (int qt = 0; qt < 2; qt++)
#pragma unroll
      for (int r = 0; r < 4; r++) {
        const int cgl = wt * 128 + ct * 16 + lhi * 4 + r;
        const int n = n0 + wq * 32 + qt * 16 + l16;
        const size_t off = (size_t)cgl * 4096 + n;
        o0[off] = oacc[ct][qt][r] + bf2f(QTb[off]);
      }
#undef STAGE_K16
#undef STAGE_VT16
#undef PS_WRITE
}

// ---------- k_ptq v7: r19's v4 structure (split-K 8, grid 512) + bf16 partials ----------
// r20 post-mortem: split-K 4 (grid 256 = 1 block/CU) cost the TLP that hides
// staging latency. Revert to split-K 8 / grid 512 / 2 blocks/CU; keep only the
// TLP-neutral half of r20's change: bf16 partial stores (32 -> 16 MB).
__global__ __launch_bounds__(256, 2) void k_ptq(
    const unsigned short* __restrict__ PTg, const unsigned short* __restrict__ QTg,
    unsigned short* __restrict__ part) {
  __shared__ char smem[65536];

  const int tid = threadIdx.x;
  const int wave = tid >> 6, lane = tid & 63;
  const int l16 = lane & 15, lhi = lane >> 4;
  const int bid = blockIdx.x;
  const int t0 = (bid >> 6) * 64;
  const int grp = bid & 63;
  const int b = grp & 7, ksl = grp >> 3;
  const int cx = (l16 & 7) << 4;

  const unsigned short* PTrow =
      PTg + ((size_t)(b * 512 + t0 + wave * 16 + l16)) * 4096 + ksl * 512 + lhi * 8;
  const char* QTb = (const char*)(QTg + (size_t)b * 256 * 4096 + ksl * 512);

#define STAGE_Q(c_, buf_) do {                                              \
    _Pragma("unroll")                                                       \
    for (int i = 0; i < 8; i++) {                                           \
      const int off = (tid + i * 256) * 16;                                 \
      const int r_ = off >> 7, ic_ = off & 127;                             \
      gload16(QTb + (size_t)r_ * 8192 + (c_) * 128 + (ic_ ^ ((r_ & 7) << 4)), \
              smem + (buf_) * 32768 + off);                                 \
    } } while (0)

  float4v acc[16];
#pragma unroll
  for (int ct = 0; ct < 16; ct++) acc[ct] = (float4v)0.f;

  STAGE_Q(0, 0);
  __syncthreads();
#pragma unroll
  for (int c = 0; c < 8; c++) {
    const int buf = c & 1;
    short8v pa0 = *(const short8v*)(PTrow + c * 64);
    short8v pa1 = *(const short8v*)(PTrow + c * 64 + 32);
    if (c < 7) STAGE_Q(c + 1, buf ^ 1);
#pragma unroll
    for (int ct = 0; ct < 16; ct++) {
      const int row = ct * 16 + l16;             // row&7 == l16&7
      const char* rb = smem + buf * 32768 + row * 128;
      short8v b0 = *(const short8v*)(rb + ((lhi * 16) ^ cx));
      acc[ct] = MFMA16(pa0, b0, acc[ct]);
      short8v b1 = *(const short8v*)(rb + ((64 + lhi * 16) ^ cx));
      acc[ct] = MFMA16(pa1, b1, acc[ct]);
    }
    __syncthreads();
  }

  // partial[ksl][b][t][c] bf16 stores (l16 -> 16 contiguous c)
  unsigned short* pout = part + (((size_t)ksl * 8 + b) * 512 + t0 + wave * 16) * 256;
#pragma unroll
  for (int ct = 0; ct < 16; ct++)
#pragma unroll
    for (int r = 0; r < 4; r++)
      pout[(lhi * 4 + r) * 256 + ct * 16 + l16] = f2bf(acc[ct][r]);
#undef STAGE_Q
}

// ---------- k_red v3: out1 = sum over 8 bf16 partials ----------
// grid 512 x 256 thr; each thread sums 8 elements (short8v loads).
__global__ __launch_bounds__(256) void k_red(
    const unsigned short* __restrict__ part, float* __restrict__ out1) {
  const size_t g = (size_t)(blockIdx.x * 256 + threadIdx.x) * 8;
  float s[8];
#pragma unroll
  for (int j = 0; j < 8; j++) s[j] = 0.f;
#pragma unroll
  for (int ksl = 0; ksl < 8; ksl++) {
    short8v v = *(const short8v*)(part + (size_t)ksl * 1048576 + g);
#pragma unroll
    for (int j = 0; j < 8; j++) s[j] += bf2f((unsigned short)v[j]);
  }
  float4 o0 = {s[0], s[1], s[2], s[3]};
  float4 o1 = {s[4], s[5], s[6], s[7]};
  *(float4*)(out1 + g) = o0;
  *(float4*)(out1 + g + 4) = o1;
}

extern "C" void kernel_launch(void* const* d_in, const int* in_sizes, int n_in,
                              void* d_out, int out_size, void* d_ws, size_t ws_size,
                              hipStream_t stream) {
  const float* Fs = (const float*)d_in[0];   // [8][256][4096]
  const float* Ft = (const float*)d_in[1];   // [8][512][256]
  float* out0 = (float*)d_out;               // [8][256][4096]
  float* out1 = out0 + (size_t)8 * 256 * 4096;  // [8][512][256]

  unsigned short* ws = (unsigned short*)d_ws;
  unsigned short* Q  = ws;                // [8][4096][256]  16 MB
  unsigned short* QT = Q + 8388608;       // [8][256][4096]  16 MB
  unsigned short* K  = QT + 8388608;      // [8][512][256]    2 MB
  unsigned short* VT = K + 1048576;       // [8][256][512]    2 MB
  unsigned short* PT = VT + 1048576;      // [8][512][4096]  32 MB
  unsigned short* part = PT + 16777216;   // [8][8][512][256] bf16, 16 MB
  // total ws use: 84,934,656 bytes

  k_cast_transpose<<<dim3(128, 8, 8), 256, 0, stream>>>(Fs, QT, Q, 256, 4096);
  k_cast_transpose<<<dim3(8, 16, 8), 256, 0, stream>>>(Ft, K, VT, 512, 256);
  k_attn<<<dim3(512), 256, 0, stream>>>(Q, K, VT, QT, out0, PT);
  k_ptq<<<dim3(512), 256, 0, stream>>>(PT, QT, part);
  k_red<<<dim3(512), 256, 0, stream>>>(part, out1);
}